// Round 15
// baseline (539.410 us; speedup 1.0000x reference)
//
#include <hip/hip_runtime.h>

#define NN 100000
#define NE 1200000
#define NG 512
#define D 64
#define NCLS 10
#define NB_N ((NN + 255) / 256)   // 391
#define NB_E ((NE + 255) / 256)   // 4688

// ---------------- CSR build (exact; no truncation) ----------------
__global__ __launch_bounds__(256) void k_hist(const int* __restrict__ ei, int* __restrict__ deg) {
    int e = blockIdx.x * 256 + threadIdx.x;
    if (e < NE) atomicAdd(&deg[ei[e]], 1);  // row = target node
}

__global__ __launch_bounds__(256) void k_scan1(const int* __restrict__ deg,
                                               int* __restrict__ starts,
                                               int* __restrict__ bsum) {
    __shared__ int sh[256];
    int i = blockIdx.x * 256 + threadIdx.x;
    int v = (i < NN) ? deg[i] : 0;
    sh[threadIdx.x] = v;
    __syncthreads();
    for (int off = 1; off < 256; off <<= 1) {
        int u = (threadIdx.x >= off) ? sh[threadIdx.x - off] : 0;
        __syncthreads();
        sh[threadIdx.x] += u;
        __syncthreads();
    }
    if (i < NN) starts[i] = sh[threadIdx.x] - v;  // exclusive within block
    if (threadIdx.x == 255) bsum[blockIdx.x] = sh[255];
}

__global__ __launch_bounds__(512) void k_scan2(int* __restrict__ bsum) {
    __shared__ int sh[512];
    int t = threadIdx.x;
    int v = (t < NB_N) ? bsum[t] : 0;
    sh[t] = v;
    __syncthreads();
    for (int off = 1; off < 512; off <<= 1) {
        int u = (t >= off) ? sh[t - off] : 0;
        __syncthreads();
        sh[t] += u;
        __syncthreads();
    }
    if (t < NB_N) bsum[t] = sh[t] - v;  // exclusive
}

__global__ __launch_bounds__(256) void k_scan3(const int* __restrict__ deg,
                                               int* __restrict__ starts,
                                               int* __restrict__ next,
                                               float* __restrict__ dinv,
                                               const int* __restrict__ bsum) {
    int i = blockIdx.x * 256 + threadIdx.x;
    if (i >= NN) return;
    int s = starts[i] + bsum[blockIdx.x];
    starts[i] = s;
    next[i] = s;
    dinv[i] = rsqrtf((float)deg[i] + 1.0f);  // +1 self-loop, always > 0
    if (i == 0) starts[NN] = NE;
}

__global__ __launch_bounds__(256) void k_fill(const int* __restrict__ ei,
                                              int* __restrict__ next,
                                              int* __restrict__ cols) {
    int e = blockIdx.x * 256 + threadIdx.x;
    if (e >= NE) return;
    int r = ei[e];
    int pos = atomicAdd(&next[r], 1);
    cols[pos] = ei[NE + e];
}

// ---- per-graph node counts (sort-independent) ----
__global__ __launch_bounds__(256) void k_cnt(const int* __restrict__ batch,
                                             float* __restrict__ cntG) {
    int i = blockIdx.x * 256 + threadIdx.x;
    if (i < NN) atomicAdd(&cntG[batch[i]], 1.0f);
}

// ---- fused GCN conv: o[n] = relu( (dinv[n]*(dinv[n]*h[n] + sum_c dinv[c]*h[c])) @ W + b )
// One wave = 8 nodes; lane j = feature j. ALL cross-lane traffic via per-wave LDS
// staging (DS ops are in-order within a wave; no barriers needed) — NO readlane.
template <bool WRITE_H>
__global__ __launch_bounds__(256) void k_conv(const int* __restrict__ starts,
                                              const int* __restrict__ cols,
                                              const float* __restrict__ dinv,
                                              const float* __restrict__ h_in,
                                              const float* __restrict__ W,
                                              const float* __restrict__ b,
                                              const int* __restrict__ batch,
                                              float* __restrict__ pool_sum,
                                              float* __restrict__ h_out) {
    __shared__ int   cbuf[4][64];   // per-wave neighbor indices
    __shared__ float dbuf[4][64];   // per-wave neighbor dinv
    __shared__ float sbuf[4][64];   // per-wave aggregated row (GEMM input)
    int w = threadIdx.x >> 6;
    int j = threadIdx.x & 63;
    int wid = blockIdx.x * 4 + w;               // 3125 blocks * 4 waves = 12500
    float wreg[64];
#pragma unroll
    for (int k = 0; k < 64; ++k) wreg[k] = W[k * 64 + j];  // coalesced, L1-hot
    float bj = b[j];
    int n0 = wid * 8;                            // 12500 * 8 = NN exactly

    for (int t = 0; t < 8; ++t) {
        int n = n0 + t;
        int s0 = starts[n], s1 = starts[n + 1];
        float dn = dinv[n];
        float a0 = dn * h_in[(size_t)n * D + j]; // self-loop term
        float a1 = 0.0f, a2 = 0.0f, a3 = 0.0f;
        for (int base = s0; base < s1; base += 64) {
            int bc = s1 - base; if (bc > 64) bc = 64;
            if (j < bc) {
                int c = cols[base + j];          // coalesced list load
                cbuf[w][j] = c;
                dbuf[w][j] = dinv[c];            // gathered
            }
            // same-wave DS in-order: reads below observe writes above
            int i = 0;
            for (; i + 4 <= bc; i += 4) {
                int c0 = cbuf[w][i],     c1 = cbuf[w][i + 1];
                int c2 = cbuf[w][i + 2], c3 = cbuf[w][i + 3];
                float d0 = dbuf[w][i],     d1 = dbuf[w][i + 1];
                float d2 = dbuf[w][i + 2], d3 = dbuf[w][i + 3];
                float h0 = h_in[(size_t)c0 * D + j];   // coalesced row gathers
                float h1 = h_in[(size_t)c1 * D + j];
                float h2 = h_in[(size_t)c2 * D + j];
                float h3 = h_in[(size_t)c3 * D + j];
                a0 += d0 * h0; a1 += d1 * h1; a2 += d2 * h2; a3 += d3 * h3;
            }
            for (; i < bc; ++i) {
                a0 += dbuf[w][i] * h_in[(size_t)cbuf[w][i] * D + j];
            }
        }
        float s = dn * ((a0 + a1) + (a2 + a3));
        sbuf[w][j] = s;                          // stage GEMM input row
        // GEMM row: LDS-broadcast reads (same addr across lanes), 4 partial accums
        float o0 = bj, o1 = 0.0f, o2 = 0.0f, o3 = 0.0f;
#pragma unroll
        for (int k = 0; k < 64; k += 4) {
            o0 += sbuf[w][k]     * wreg[k];
            o1 += sbuf[w][k + 1] * wreg[k + 1];
            o2 += sbuf[w][k + 2] * wreg[k + 2];
            o3 += sbuf[w][k + 3] * wreg[k + 3];
        }
        float o = fmaxf((o0 + o1) + (o2 + o3), 0.0f);
        if (WRITE_H) h_out[(size_t)n * D + j] = o;
        int g = batch[n];
        atomicAdd(&pool_sum[(size_t)g * D + j], o);  // per-graph sum (mean later)
    }
}

// ---- head: out[g] = log_softmax(relu(((sum1+sum2)/denom)@Wl + bl)), fp32 out ----
// One wave per graph; plain LDS + __syncthreads, no cross-lane intrinsics.
__global__ __launch_bounds__(64) void k_head(const float* __restrict__ pool1,
                                             const float* __restrict__ pool2,
                                             const float* __restrict__ cntG,
                                             const float* __restrict__ Wl,
                                             const float* __restrict__ bl,
                                             float* __restrict__ out) {
    __shared__ float pz[64];
    __shared__ float zz[NCLS];
    __shared__ float msh[2];
    int g = blockIdx.x;
    int j = threadIdx.x;
    float denom = fmaxf(cntG[g], 1.0f);
    pz[j] = (pool1[(size_t)g * D + j] + pool2[(size_t)g * D + j]) / denom;  // x1+x2
    __syncthreads();
    if (j < NCLS) {
        float z = bl[j];
#pragma unroll
        for (int k = 0; k < 64; ++k) z += pz[k] * Wl[k * NCLS + j];
        zz[j] = fmaxf(z, 0.0f);
    }
    __syncthreads();
    if (j == 0) {
        float m = zz[0];
        for (int q = 1; q < NCLS; ++q) m = fmaxf(m, zz[q]);
        float se = 0.0f;
        for (int q = 0; q < NCLS; ++q) se += expf(zz[q] - m);
        msh[0] = m;
        msh[1] = logf(se);
    }
    __syncthreads();
    if (j < NCLS) out[g * NCLS + j] = zz[j] - msh[0] - msh[1];
}

extern "C" void kernel_launch(void* const* d_in, const int* in_sizes, int n_in,
                              void* d_out, int out_size, void* d_ws, size_t ws_size,
                              hipStream_t stream) {
    const float* x   = (const float*)d_in[0];    // fp32 [NN,64]
    const int* ei    = (const int*)d_in[1];      // int32 [2,NE]
    const int* batch = (const int*)d_in[2];      // int32 [NN] (no sortedness assumed)
    const float* W1  = (const float*)d_in[3];    // fp32 [64,64]
    const float* b1  = (const float*)d_in[4];
    const float* W2  = (const float*)d_in[5];
    const float* b2  = (const float*)d_in[6];
    const float* Wl  = (const float*)d_in[7];    // fp32 [64,10]
    const float* bl  = (const float*)d_in[8];
    float* out = (float*)d_out;                  // fp32 [NG,NCLS]

    // workspace layout (4-byte elems). Total ~30.8 MiB (identical to R14).
    int*   deg    = (int*)d_ws;                  // NN   (zeroed each call)
    int*   starts = deg + NN;                    // NN+1 (padded to NN+16)
    int*   next   = starts + NN + 16;            // NN
    int*   bsum   = next + NN;                   // 512
    float* dinv   = (float*)(bsum + 512);        // NN
    int*   cols   = (int*)(dinv + NN);           // NE (exact CSR)
    float* bufA   = (float*)(cols + NE);         // NN*D (h1 only)
    float* pool1  = bufA + (size_t)NN * D;       // NG*D (atomic sums, zeroed)
    float* pool2  = pool1 + (size_t)NG * D;      // NG*D (atomic sums, zeroed)
    float* cntG   = pool2 + (size_t)NG * D;      // NG   (atomic counts, zeroed)

    const int nblk_conv = NN / 32;               // 3125 (4 waves * 8 nodes)

    // ---- zero accumulators (pools + counts contiguous) ----
    hipMemsetAsync(deg, 0, NN * sizeof(int), stream);
    hipMemsetAsync(pool1, 0, (2 * NG * D + NG) * sizeof(float), stream);

    // ---- CSR build (amortized over both convs) ----
    k_hist<<<NB_E, 256, 0, stream>>>(ei, deg);
    k_scan1<<<NB_N, 256, 0, stream>>>(deg, starts, bsum);
    k_scan2<<<1, 512, 0, stream>>>(bsum);
    k_scan3<<<NB_N, 256, 0, stream>>>(deg, starts, next, dinv, bsum);
    k_fill<<<NB_E, 256, 0, stream>>>(ei, next, cols);

    // ---- per-graph node counts ----
    k_cnt<<<NB_N, 256, 0, stream>>>(batch, cntG);

    // ---- conv1: h1 = relu((A x) W1 + b1); pool1 += h1 per graph ----
    k_conv<true><<<nblk_conv, 256, 0, stream>>>(starts, cols, dinv, x, W1, b1,
                                                batch, pool1, bufA);

    // ---- conv2: h2 = relu((A h1) W2 + b2); pool2 += h2 per graph (h2 never stored) ----
    k_conv<false><<<nblk_conv, 256, 0, stream>>>(starts, cols, dinv, bufA, W2, b2,
                                                 batch, pool2, nullptr);

    // ---- head ----
    k_head<<<NG, 64, 0, stream>>>(pool1, pool2, cntG, Wl, bl, out);
}